// Round 11
// baseline (689.402 us; speedup 1.0000x reference)
//
#include <hip/hip_runtime.h>
#include <hip/hip_bf16.h>
#include <stdint.h>

// LayerNormLSTM: T=512, B=64, I=1024, H=1024
// M = T*B = 32768 rows, N = 4*H = 4096, K = 1024.
// Reference degenerates (h0=c0=0, no scan):
//   h2h_vec = LN(bh; g_h2h, b_h2h)            (constant 4096-vec; Wh unused)
//   y       = x @ Wi^T                         (big GEMM)
//   p       = g_i2h * LNrow(y + bi) + (b_i2h + h2h_vec)
//   f,o     = sigmoid(p[H:2H]), sigmoid(p[2H:3H]); g = tanh(p[3H:])
//   c       = (1-f)*g ;  cn = LN_H(c) ;  h = o * tanh(cn)
// out = [h (T,B,H) ; h[-1] (B,H)]
//
// Scratch: d_ws: [0,64MB) xb | [64MB,72MB) wb | [72MB,136MB) Y | [136MB,200MB) yscr
//
// R11 = ABLATION ROUND (real pipeline identical to R10). Six schedule
// variants all sit at ~6300 cyc/tile vs the ~3400 serialized-window floor;
// per skill rule "ablate before optimizing", two variants run into scratch:
//   abl_nostage: phases+barriers+reads kept, staging/vmcnt removed.
//   abl_noread : staging+vmcnt+barriers+MFMA kept, ds_reads hoisted out.
// Both 1024 blocks (so they rank above the 84us real dispatches in top-5),
// deterministic, write-only to yscr (never read). One-time dur_us cost.

#define MROWS 32768L
#define NCOLS 4096
#define KDIM  1024

typedef __bf16 bf16x8 __attribute__((ext_vector_type(8)));
typedef __bf16 bf16x4 __attribute__((ext_vector_type(4)));
typedef float  f32x4  __attribute__((ext_vector_type(4)));

__device__ float g_Cvec[4096];   // b_i2h + h2h_vec (recomputed every launch)

__device__ __forceinline__ void gload16(char* lds, const char* g) {
  __builtin_amdgcn_global_load_lds(
      (const __attribute__((address_space(1))) char*)g,
      (__attribute__((address_space(3))) char*)lds, 16, 0, 0);
}

__device__ __forceinline__ void block_reduce2(float& a, float& b, float* red, int tid) {
#pragma unroll
  for (int m = 32; m > 0; m >>= 1) {
    a += __shfl_xor(a, m, 64);
    b += __shfl_xor(b, m, 64);
  }
  const int lane = tid & 63, wid = tid >> 6;
  if (lane == 0) { red[wid] = a; red[4 + wid] = b; }
  __syncthreads();
  a = red[0] + red[1] + red[2] + red[3];
  b = red[4] + red[5] + red[6] + red[7];
  __syncthreads();  // safe reuse of red[]
}

// ---------------- cast f32 -> bf16 (vectorized) ----------------
__global__ __launch_bounds__(256) void cast_kernel(const float4* __restrict__ in,
                                                   bf16x4* __restrict__ out, int n4) {
  int i = blockIdx.x * 256 + threadIdx.x;
  const int stride = gridDim.x * 256;
  for (; i < n4; i += stride) {
    const float4 v = in[i];
    bf16x4 o = { (__bf16)v.x, (__bf16)v.y, (__bf16)v.z, (__bf16)v.w };
    out[i] = o;
  }
}

// ---------------- prep: Cvec = b_i2h + LN(bh)*g_h2h + b_h2h ----------------
__global__ __launch_bounds__(256) void prep_kernel(const float* __restrict__ bh,
                                                   const float* __restrict__ b_i2h,
                                                   const float* __restrict__ g_h2h,
                                                   const float* __restrict__ b_h2h) {
  __shared__ float red[8];
  const int tid = threadIdx.x;
  float v[16];
  float s = 0.f, ss = 0.f;
#pragma unroll
  for (int u = 0; u < 16; ++u) {
    v[u] = bh[tid + u * 256];
    s += v[u]; ss += v[u] * v[u];
  }
  block_reduce2(s, ss, red, tid);
  const float mu  = s * (1.f / 4096.f);
  const float var = (ss - 4096.f * mu * mu) * (1.f / 4095.f);   // ddof=1
  const float rs  = rsqrtf(var + 1e-6f);
#pragma unroll
  for (int u = 0; u < 16; ++u) {
    const int g = tid + u * 256;
    g_Cvec[g] = b_i2h[g] + g_h2h[g] * ((v[u] - mu) * rs) + b_h2h[g];
  }
}

// ---------------- shared GEMM machinery ----------------
#define BAR()   __builtin_amdgcn_s_barrier()
#define VMCNT(n) asm volatile("s_waitcnt vmcnt(" #n ")" ::: "memory")
#define SETP1() __builtin_amdgcn_s_setprio(1)
#define SETP0() __builtin_amdgcn_s_setprio(0)
#define CFENCE() asm volatile("" ::: "memory")

#define STG_A(s, h) { char* d_ = Al + (((s) & 1) << 15) + ((h) << 14); \
    const char* g_ = Ag + (long)(h) * 262144 + (s) * 128; \
    gload16(d_, g_); gload16(d_ + 8192, g_ + 131072); }

#define STG_B(s, h) { char* d_ = Bl + (((s) & 1) << 15) + ((h) << 14); \
    const char* g_ = Bg + (long)(h) * 262144 + (s) * 128; \
    gload16(d_, g_); gload16(d_ + 8192, g_ + 131072); }

#define ABASE(t) ((const char*)As + (((t) & 1) << 15) + (wr << 14))
#define BBASE(t) ((const char*)Bs + (((t) & 1) << 15) + ((wc >> 1) << 14))

#define RD_Ax(arr, Ahalf, c) { _Pragma("unroll") for (int mi_ = 0; mi_ < 4; ++mi_) { \
    const char* p_ = (Ahalf) + (((c) * 64 + mi_ * 16 + fr) << 7); \
    arr[mi_][0] = *(const bf16x8*)(p_ + cb0); \
    arr[mi_][1] = *(const bf16x8*)(p_ + cb1); } }

#define RD_Bx(arr, Bhalf, g) { _Pragma("unroll") for (int nj_ = 0; nj_ < 2; ++nj_) { \
    const char* p_ = (Bhalf) + ((brow0 + (g) * 32 + nj_ * 16 + fr) << 7); \
    arr[nj_][0] = *(const bf16x8*)(p_ + cb0); \
    arr[nj_][1] = *(const bf16x8*)(p_ + cb1); } }

#define MMQ(X, Y, c, g) { _Pragma("unroll") for (int mi_ = 0; mi_ < 4; ++mi_) { \
    _Pragma("unroll") for (int nj_ = 0; nj_ < 2; ++nj_) { \
      acc[(c)*4+mi_][(g)*2+nj_] = __builtin_amdgcn_mfma_f32_16x16x32_bf16( \
          X[mi_][0], Y[nj_][0], acc[(c)*4+mi_][(g)*2+nj_], 0, 0, 0); \
      acc[(c)*4+mi_][(g)*2+nj_] = __builtin_amdgcn_mfma_f32_16x16x32_bf16( \
          X[mi_][1], Y[nj_][1], acc[(c)*4+mi_][(g)*2+nj_], 0, 0, 0); } } }

#define GEMM_COMMON_SETUP(AROWS_MASK) \
  const int tid  = threadIdx.x; \
  const int lane = tid & 63; \
  const int wid  = tid >> 6; \
  const int wr   = wid >> 2; \
  const int wc   = wid & 3; \
  const int nwg = gridDim.x; \
  const int q8 = nwg >> 3, r8 = nwg & 7; \
  const int xcd = blockIdx.x & 7, rest = blockIdx.x >> 3; \
  const int wgid = (xcd < r8 ? xcd * (q8 + 1) : r8 * (q8 + 1) + (xcd - r8) * q8) + rest; \
  const long m0 = (long)(wgid >> 4) * 256; \
  const long n0 = (long)(wgid & 15) * 256; \
  const int scol = (((tid & 7) ^ ((tid >> 3) & 7)) << 4); \
  const char* Ag = (const char*)(A + (r0 + m0) * KDIM) + (long)(tid >> 3) * 2048 + scol; \
  const char* Bg = (const char*)(B + n0 * KDIM) + (long)(tid >> 3) * 2048 + scol; \
  char* Al = (char*)As + tid * 16; \
  char* Bl = (char*)Bs + tid * 16; \
  const int fr  = lane & 15; \
  const int sw  = (fr & 7) << 4; \
  const int cb0 = (((lane >> 4) << 4)) ^ sw; \
  const int cb1 = (64 | ((lane >> 4) << 4)) ^ sw; \
  const int brow0 = (wc & 1) << 6; \
  f32x4 acc[8][4]; \
  const f32x4 z = {0.f, 0.f, 0.f, 0.f}; \
  _Pragma("unroll") for (int i = 0; i < 8; ++i) \
    _Pragma("unroll") for (int j = 0; j < 4; ++j) acc[i][j] = z; \
  bf16x8 A0[4][2], A1[4][2], B01[2][2], B23[2][2];

#define GEMM_EPILOGUE(MBASE) \
  const long mrow = (MBASE) + wr * 128 + ((lane >> 4) << 2); \
  const long ncol = n0 + wc * 64 + fr; \
  __bf16* Yp = Y + mrow * NCOLS + ncol; \
  _Pragma("unroll") for (int c = 0; c < 2; ++c) \
    _Pragma("unroll") for (int mi = 0; mi < 4; ++mi) \
      _Pragma("unroll") for (int nj = 0; nj < 4; ++nj) \
        _Pragma("unroll") for (int r = 0; r < 4; ++r) \
          Yp[(long)(c * 64 + mi * 16 + r) * NCOLS + nj * 16] = (__bf16)acc[c * 4 + mi][nj][r];

// ---------------- real GEMM (identical to R10) ----------------
// S1 = (t+2 < 16), S2 = (t+3 < 16); VMA at P3, VMB at P7.
#define TWOTILE(t, S1, S2, VMA, VMB) { \
    const char* At_ = ABASE(t); const char* Bt_ = BBASE(t); \
    const char* Au_ = ABASE((t) + 1); const char* Bu_ = BBASE((t) + 1); \
    /*P0*/ RD_Ax(A0, At_, 0); RD_Bx(B01, Bt_, 0); \
           BAR(); SETP1(); MMQ(A0, B01, 0, 0); SETP0(); BAR(); \
    /*P1*/ RD_Ax(A1, At_, 1); \
           BAR(); SETP1(); MMQ(A1, B01, 1, 0); SETP0(); BAR(); \
    /*P2*/ RD_Bx(B23, Bt_, 1); if (S1) { STG_A((t) + 2, 0); STG_A((t) + 2, 1); } \
           BAR(); SETP1(); MMQ(A1, B23, 1, 1); SETP0(); BAR(); \
    /*P3*/ if (S1) { STG_B((t) + 2, 0); STG_B((t) + 2, 1); } VMA; \
           BAR(); SETP1(); MMQ(A0, B23, 0, 1); SETP0(); BAR(); \
    /*P4*/ RD_Ax(A0, Au_, 0); RD_Bx(B01, Bu_, 0); \
           BAR(); SETP1(); MMQ(A0, B01, 0, 0); SETP0(); BAR(); \
    /*P5*/ RD_Ax(A1, Au_, 1); \
           BAR(); SETP1(); MMQ(A1, B01, 1, 0); SETP0(); BAR(); \
    /*P6*/ RD_Bx(B23, Bu_, 1); if (S2) { STG_A((t) + 3, 0); STG_A((t) + 3, 1); } \
           BAR(); SETP1(); MMQ(A1, B23, 1, 1); SETP0(); BAR(); \
    /*P7*/ if (S2) { STG_B((t) + 3, 0); STG_B((t) + 3, 1); } VMB; \
           BAR(); SETP1(); MMQ(A0, B23, 0, 1); SETP0(); BAR(); }

__global__ __launch_bounds__(512, 2) void gemm_kernel(const __bf16* __restrict__ A,
                                                      const __bf16* __restrict__ B,
                                                      __bf16* __restrict__ Y, long r0) {
  __shared__ __align__(16) __bf16 As[2 * 2 * 8192];
  __shared__ __align__(16) __bf16 Bs[2 * 2 * 8192];
  GEMM_COMMON_SETUP(~0L)

  STG_A(0, 0); STG_A(0, 1); STG_B(0, 0); STG_B(0, 1);
  STG_A(1, 0); STG_A(1, 1); STG_B(1, 0); STG_B(1, 1);
  VMCNT(8);
  BAR();

#pragma unroll 1
  for (int tt = 0; tt < 7; ++tt) {
    const int t = tt * 2;
    TWOTILE(t, true, true, VMCNT(8), VMCNT(8));
  }
  TWOTILE(14, false, false, VMCNT(0), ((void)0));

  GEMM_EPILOGUE(m0)
}

// ---------------- ablation 1: no staging (reads+barriers+MFMA only) ----------
__global__ __launch_bounds__(512, 2) void gemm_abl_nostage(const __bf16* __restrict__ A,
                                                           const __bf16* __restrict__ B,
                                                           __bf16* __restrict__ Y) {
  __shared__ __align__(16) __bf16 As[2 * 2 * 8192];
  __shared__ __align__(16) __bf16 Bs[2 * 2 * 8192];
  const long r0 = 0;
  GEMM_COMMON_SETUP(~0L)

  STG_A(0, 0); STG_A(0, 1); STG_B(0, 0); STG_B(0, 1);
  VMCNT(0);
  BAR();
  const char* At_ = ABASE(0); const char* Bt_ = BBASE(0);

#pragma unroll 1
  for (int t = 0; t < 16; ++t) {
    // CFENCE forces genuine re-reads each phase (no cross-iteration CSE).
    CFENCE(); RD_Ax(A0, At_, 0); RD_Bx(B01, Bt_, 0);
    BAR(); SETP1(); MMQ(A0, B01, 0, 0); SETP0(); BAR();
    CFENCE(); RD_Ax(A1, At_, 1);
    BAR(); SETP1(); MMQ(A1, B01, 1, 0); SETP0(); BAR();
    CFENCE(); RD_Bx(B23, Bt_, 1);
    BAR(); SETP1(); MMQ(A1, B23, 1, 1); SETP0(); BAR();
    BAR(); SETP1(); MMQ(A0, B23, 0, 1); SETP0(); BAR();
  }

  GEMM_EPILOGUE(m0 & 8191)
}

// ---------------- ablation 2: no ds_reads (stages+vmcnt+barriers+MFMA) -------
#define TWOTILE_NR(t, S1, S2, VMA, VMB) { \
    /*P0*/ BAR(); SETP1(); MMQ(A0, B01, 0, 0); SETP0(); BAR(); \
    /*P1*/ BAR(); SETP1(); MMQ(A1, B01, 1, 0); SETP0(); BAR(); \
    /*P2*/ if (S1) { STG_A((t) + 2, 0); STG_A((t) + 2, 1); } \
           BAR(); SETP1(); MMQ(A1, B23, 1, 1); SETP0(); BAR(); \
    /*P3*/ if (S1) { STG_B((t) + 2, 0); STG_B((t) + 2, 1); } VMA; \
           BAR(); SETP1(); MMQ(A0, B23, 0, 1); SETP0(); BAR(); \
    /*P4*/ BAR(); SETP1(); MMQ(A0, B01, 0, 0); SETP0(); BAR(); \
    /*P5*/ BAR(); SETP1(); MMQ(A1, B01, 1, 0); SETP0(); BAR(); \
    /*P6*/ if (S2) { STG_A((t) + 3, 0); STG_A((t) + 3, 1); } \
           BAR(); SETP1(); MMQ(A1, B23, 1, 1); SETP0(); BAR(); \
    /*P7*/ if (S2) { STG_B((t) + 3, 0); STG_B((t) + 3, 1); } VMB; \
           BAR(); SETP1(); MMQ(A0, B23, 0, 1); SETP0(); BAR(); }

__global__ __launch_bounds__(512, 2) void gemm_abl_noread(const __bf16* __restrict__ A,
                                                          const __bf16* __restrict__ B,
                                                          __bf16* __restrict__ Y) {
  __shared__ __align__(16) __bf16 As[2 * 2 * 8192];
  __shared__ __align__(16) __bf16 Bs[2 * 2 * 8192];
  const long r0 = 0;
  GEMM_COMMON_SETUP(~0L)

  STG_A(0, 0); STG_A(0, 1); STG_B(0, 0); STG_B(0, 1);
  STG_A(1, 0); STG_A(1, 1); STG_B(1, 0); STG_B(1, 1);
  VMCNT(8);
  BAR();
  // hoisted fragment reads (once)
  { const char* At_ = ABASE(0); const char* Bt_ = BBASE(0);
    RD_Ax(A0, At_, 0); RD_Ax(A1, At_, 1); RD_Bx(B01, Bt_, 0); RD_Bx(B23, Bt_, 1); }

#pragma unroll 1
  for (int tt = 0; tt < 7; ++tt) {
    const int t = tt * 2;
    TWOTILE_NR(t, true, true, VMCNT(8), VMCNT(8));
  }
  TWOTILE_NR(14, false, false, VMCNT(0), ((void)0));

  GEMM_EPILOGUE(m0 & 8191)
}

// ---------------- pass 2: row LN + gates + cell LN + output ----------------
__global__ __launch_bounds__(256) void pass2_kernel(const __bf16* __restrict__ Yw,
                                                    const float* __restrict__ bi,
                                                    const float* __restrict__ g_i2h,
                                                    const float* __restrict__ g_cell,
                                                    const float* __restrict__ b_cell,
                                                    float* __restrict__ out, long r0) {
  __shared__ float p0[4096];
  __shared__ float red[8];
  const int tid  = threadIdx.x;
  const long row = r0 + blockIdx.x;           // global row (t*64 + b)
  const bf16x8* yv = (const bf16x8*)(Yw + (long)blockIdx.x * NCOLS);

  float s = 0.f, ss = 0.f;
#pragma unroll
  for (int it = 0; it < 2; ++it) {
    const int ch = tid + it * 256;
    const bf16x8 v = yv[ch];
    const float4 b0 = ((const float4*)bi)[ch * 2];
    const float4 b1 = ((const float4*)bi)[ch * 2 + 1];
    float p[8];
    p[0] = (float)v[0] + b0.x;  p[1] = (float)v[1] + b0.y;
    p[2] = (float)v[2] + b0.z;  p[3] = (float)v[3] + b0.w;
    p[4] = (float)v[4] + b1.x;  p[5] = (float)v[5] + b1.y;
    p[6] = (float)v[6] + b1.z;  p[7] = (float)v[7] + b1.w;
#pragma unroll
    for (int u = 0; u < 8; ++u) {
      p0[ch * 8 + u] = p[u];
      s += p[u];
      ss += p[u] * p[u];
    }
  }
  block_reduce2(s, ss, red, tid);
  const float mu  = s * (1.f / 4096.f);
  const float var = (ss - 4096.f * mu * mu) * (1.f / 4095.f);   // ddof=1
  const float rs  = rsqrtf(var + 1e-6f);

  float cc[4], oo[4];
  float s2 = 0.f, ss2 = 0.f;
#pragma unroll
  for (int u = 0; u < 4; ++u) {
    const int j = tid + u * 256;
    const float pf = g_i2h[1024 + j] * ((p0[1024 + j] - mu) * rs) + g_Cvec[1024 + j];
    const float po = g_i2h[2048 + j] * ((p0[2048 + j] - mu) * rs) + g_Cvec[2048 + j];
    const float pg = g_i2h[3072 + j] * ((p0[3072 + j] - mu) * rs) + g_Cvec[3072 + j];
    const float f  = 1.f / (1.f + __expf(-pf));
    oo[u] = 1.f / (1.f + __expf(-po));
    const float e2 = __expf(2.f * pg);
    const float gt = (e2 - 1.f) / (e2 + 1.f);   // tanh
    cc[u] = (1.f - f) * gt;                     // c0 = 0
    s2 += cc[u]; ss2 += cc[u] * cc[u];
  }
  block_reduce2(s2, ss2, red, tid);
  const float mu2  = s2 * (1.f / 1024.f);
  const float var2 = (ss2 - 1024.f * mu2 * mu2) * (1.f / 1023.f);  // ddof=1
  const float rs2  = rsqrtf(var2 + 1e-6f);

  const long obase = row * 1024;
#pragma unroll
  for (int u = 0; u < 4; ++u) {
    const int j = tid + u * 256;
    const float cn = g_cell[j] * ((cc[u] - mu2) * rs2) + b_cell[j];
    const float e2 = __expf(2.f * cn);
    const float th = (e2 - 1.f) / (e2 + 1.f);
    const float h  = oo[u] * th;
    out[obase + j] = h;
    if (row >= MROWS - 64)                       // t == T-1
      out[MROWS * 1024 + ((row - (MROWS - 64)) << 10) + j] = h;
  }
}

extern "C" void kernel_launch(void* const* d_in, const int* in_sizes, int n_in,
                              void* d_out, int out_size, void* d_ws, size_t ws_size,
                              hipStream_t stream) {
  (void)in_sizes; (void)n_in; (void)out_size;
  const float* x      = (const float*)d_in[0];
  const float* Wi     = (const float*)d_in[1];
  const float* bi     = (const float*)d_in[2];
  // d_in[3] = Wh : unused (h0 == 0)
  const float* bh     = (const float*)d_in[4];
  const float* g_i2h  = (const float*)d_in[5];
  const float* b_i2h  = (const float*)d_in[6];
  const float* g_h2h  = (const float*)d_in[7];
  const float* b_h2h  = (const float*)d_in[8];
  const float* g_cell = (const float*)d_in[9];
  const float* b_cell = (const float*)d_in[10];
  float* out = (float*)d_out;

  // d_ws layout (ws >= 256MB evidence: R1-R3 held full 256MB Y there):
  //   [0, 64MB)      xb   : x as bf16
  //   [64MB, 72MB)   wb   : Wi as bf16
  //   [72MB, 136MB)  y    : Y chunk (<= 64MB)
  //   [136MB, 200MB) yscr : ablation scratch (write-only, never read)
  __bf16* xb   = (__bf16*)d_ws;
  __bf16* wb   = (__bf16*)((char*)d_ws + 67108864);
  __bf16* y    = (__bf16*)((char*)d_ws + 75497472);
  __bf16* yscr = (__bf16*)((char*)d_ws + 142606336);

  cast_kernel<<<2048, 256, 0, stream>>>((const float4*)x, (bf16x4*)xb, 33554432 / 4);
  cast_kernel<<<1024, 256, 0, stream>>>((const float4*)Wi, (bf16x4*)wb, 4194304 / 4);
  prep_kernel<<<1, 256, 0, stream>>>(bh, b_i2h, g_h2h, b_h2h);

  // --- ablation dispatches (diagnostic, write-only to yscr) ---
  gemm_abl_nostage<<<dim3(1024), 512, 0, stream>>>(xb, wb, yscr);
  gemm_abl_noread <<<dim3(1024), 512, 0, stream>>>(xb, wb, yscr);

  // --- real pipeline (identical to R10) ---
  long avail = 67108864L;
  long max_rows = (avail / (NCOLS * 2)) & ~255L;
  if (max_rows > 8192) max_rows = 8192;
  for (long rbase = 0; rbase < MROWS; rbase += max_rows) {
    const long rows = (MROWS - rbase < max_rows) ? (MROWS - rbase) : max_rows;
    gemm_kernel<<<dim3((rows / 256) * 16), 512, 0, stream>>>(xb, wb, y, rbase);
    pass2_kernel<<<dim3(rows), 256, 0, stream>>>(y, bi, g_i2h, g_cell, b_cell, out, rbase);
  }
}

// Round 12
// 443.533 us; speedup vs baseline: 1.5543x; 1.5543x over previous
//
#include <hip/hip_runtime.h>
#include <hip/hip_bf16.h>
#include <stdint.h>

// LayerNormLSTM: T=512, B=64, I=1024, H=1024
// M = T*B = 32768 rows, N = 4*H = 4096, K = 1024.
// Reference degenerates (h0=c0=0, no scan):
//   h2h_vec = LN(bh; g_h2h, b_h2h)            (constant 4096-vec; Wh unused)
//   y       = x @ Wi^T                         (big GEMM)
//   p       = g_i2h * LNrow(y + bi) + (b_i2h + h2h_vec)
//   f,o     = sigmoid(p[H:2H]), sigmoid(p[2H:3H]); g = tanh(p[3H:])
//   c       = (1-f)*g ;  cn = LN_H(c) ;  h = o * tanh(cn)
// out = [h (T,B,H) ; h[-1] (B,H)]
//
// Scratch: d_ws only: [0,64MB) xb | [64MB,72MB) wb | [72MB,+64MB) Y
//
// R12: ASM BARRIER. R11 ablation: noread (no ds_reads) = 5062 cyc/tile vs
// 2480 MFMA floor -> the {staging+barrier} frame carries ~2000 cyc/tile.
// Convicted: __builtin_amdgcn_s_barrier() makes the waitcnt pass drain
// vmcnt(0) when global_load_lds are outstanding (guide: the m97 ~20% stall)
// -> counted vmcnt(8) never counts; all 6 schedules pinned at drain0 level.
// Fix: asm volatile("s_barrier" ::: "memory") — INLINEASM is opaque to the
// waitcnt pass (no auto-drain); "memory" keeps compiler motion fenced.
// Safety without implicit drains (re-audited):
//  - stage->read: counted VMCNT(8) + barrier = each wave passes its own
//    vmcnt before arriving; release => all waves' older loads landed.
//  - read->overwrite: every ds_read is consumed by same-phase MFMA (lgkm
//    drained by data-dep) before that wave's phase-end barrier; stages come
//    >=1 full phase later (R9 rotation).

#define MROWS 32768L
#define NCOLS 4096
#define KDIM  1024

typedef __bf16 bf16x8 __attribute__((ext_vector_type(8)));
typedef __bf16 bf16x4 __attribute__((ext_vector_type(4)));
typedef float  f32x4  __attribute__((ext_vector_type(4)));

__device__ float g_Cvec[4096];   // b_i2h + h2h_vec (recomputed every launch)

__device__ __forceinline__ void gload16(char* lds, const char* g) {
  __builtin_amdgcn_global_load_lds(
      (const __attribute__((address_space(1))) char*)g,
      (__attribute__((address_space(3))) char*)lds, 16, 0, 0);
}

__device__ __forceinline__ void block_reduce2(float& a, float& b, float* red, int tid) {
#pragma unroll
  for (int m = 32; m > 0; m >>= 1) {
    a += __shfl_xor(a, m, 64);
    b += __shfl_xor(b, m, 64);
  }
  const int lane = tid & 63, wid = tid >> 6;
  if (lane == 0) { red[wid] = a; red[4 + wid] = b; }
  __syncthreads();
  a = red[0] + red[1] + red[2] + red[3];
  b = red[4] + red[5] + red[6] + red[7];
  __syncthreads();  // safe reuse of red[]
}

// ---------------- cast f32 -> bf16 (vectorized) ----------------
__global__ __launch_bounds__(256) void cast_kernel(const float4* __restrict__ in,
                                                   bf16x4* __restrict__ out, int n4) {
  int i = blockIdx.x * 256 + threadIdx.x;
  const int stride = gridDim.x * 256;
  for (; i < n4; i += stride) {
    const float4 v = in[i];
    bf16x4 o = { (__bf16)v.x, (__bf16)v.y, (__bf16)v.z, (__bf16)v.w };
    out[i] = o;
  }
}

// ---------------- prep: Cvec = b_i2h + LN(bh)*g_h2h + b_h2h ----------------
__global__ __launch_bounds__(256) void prep_kernel(const float* __restrict__ bh,
                                                   const float* __restrict__ b_i2h,
                                                   const float* __restrict__ g_h2h,
                                                   const float* __restrict__ b_h2h) {
  __shared__ float red[8];
  const int tid = threadIdx.x;
  float v[16];
  float s = 0.f, ss = 0.f;
#pragma unroll
  for (int u = 0; u < 16; ++u) {
    v[u] = bh[tid + u * 256];
    s += v[u]; ss += v[u] * v[u];
  }
  block_reduce2(s, ss, red, tid);
  const float mu  = s * (1.f / 4096.f);
  const float var = (ss - 4096.f * mu * mu) * (1.f / 4095.f);   // ddof=1
  const float rs  = rsqrtf(var + 1e-6f);
#pragma unroll
  for (int u = 0; u < 16; ++u) {
    const int g = tid + u * 256;
    g_Cvec[g] = b_i2h[g] + g_h2h[g] * ((v[u] - mu) * rs) + b_h2h[g];
  }
}

// ---------------- GEMM: Y[m][n] = sum_k A[m][k]*B[n][k]  (bf16 in, bf16 out) ----
// 256x256x64 tile, 8 waves (2Mx4N), 128KiB LDS [2 dbuf][2 half][128][64],
// full-rank LDS swizzle (slot ^= row&7; conflicts measured 0).
// MFMA 16x16x32; per wave 128x64: acc[8][4] f32x4.
//
// 8-phase schedule (2 K-tiles t,u=t+1 per iter), R9 race-free rotation:
//   P0: RD A0(8)+B01(4);              MFMA A0xB01
//   P1: RD A1(8);                     MFMA A1xB01
//   P2: RD B23(4); STG A(t+2) h0+h1;  MFMA A1xB23
//   P3: STG B(t+2) h0+h1; vmcnt(8);   MFMA A0xB23
//   P4..P7: same for tile u, staging t+3.
// Ledger: A buf[t] last read P1 -> staged P2.  B buf[t] last read P2 ->
//   staged P3.  vmcnt(8)@P3 keeps only {A,B}(t+2) -> tile t+1 landed before
//   P4; vmcnt(8)@P7 -> t+2 landed before next P0. Prologue 16 loads +
//   vmcnt(8) -> tile0 landed. Tail t=14: no stages; P3 vmcnt(0).

#define BAR()   asm volatile("s_barrier" ::: "memory")
#define VMCNT(n) asm volatile("s_waitcnt vmcnt(" #n ")" ::: "memory")
#define SETP1() __builtin_amdgcn_s_setprio(1)
#define SETP0() __builtin_amdgcn_s_setprio(0)

#define STG_A(s, h) { char* d_ = Al + (((s) & 1) << 15) + ((h) << 14); \
    const char* g_ = Ag + (long)(h) * 262144 + (s) * 128; \
    gload16(d_, g_); gload16(d_ + 8192, g_ + 131072); }

#define STG_B(s, h) { char* d_ = Bl + (((s) & 1) << 15) + ((h) << 14); \
    const char* g_ = Bg + (long)(h) * 262144 + (s) * 128; \
    gload16(d_, g_); gload16(d_ + 8192, g_ + 131072); }

#define ABASE(t) ((const char*)As + (((t) & 1) << 15) + (wr << 14))
#define BBASE(t) ((const char*)Bs + (((t) & 1) << 15) + ((wc >> 1) << 14))

#define RD_Ax(arr, Ahalf, c) { _Pragma("unroll") for (int mi_ = 0; mi_ < 4; ++mi_) { \
    const char* p_ = (Ahalf) + (((c) * 64 + mi_ * 16 + fr) << 7); \
    arr[mi_][0] = *(const bf16x8*)(p_ + cb0); \
    arr[mi_][1] = *(const bf16x8*)(p_ + cb1); } }

#define RD_Bx(arr, Bhalf, g) { _Pragma("unroll") for (int nj_ = 0; nj_ < 2; ++nj_) { \
    const char* p_ = (Bhalf) + ((brow0 + (g) * 32 + nj_ * 16 + fr) << 7); \
    arr[nj_][0] = *(const bf16x8*)(p_ + cb0); \
    arr[nj_][1] = *(const bf16x8*)(p_ + cb1); } }

#define MMQ(X, Y, c, g) { _Pragma("unroll") for (int mi_ = 0; mi_ < 4; ++mi_) { \
    _Pragma("unroll") for (int nj_ = 0; nj_ < 2; ++nj_) { \
      acc[(c)*4+mi_][(g)*2+nj_] = __builtin_amdgcn_mfma_f32_16x16x32_bf16( \
          X[mi_][0], Y[nj_][0], acc[(c)*4+mi_][(g)*2+nj_], 0, 0, 0); \
      acc[(c)*4+mi_][(g)*2+nj_] = __builtin_amdgcn_mfma_f32_16x16x32_bf16( \
          X[mi_][1], Y[nj_][1], acc[(c)*4+mi_][(g)*2+nj_], 0, 0, 0); } } }

// S1 = (t+2 < 16), S2 = (t+3 < 16); VMA at P3, VMB at P7.
#define TWOTILE(t, S1, S2, VMA, VMB) { \
    const char* At_ = ABASE(t); const char* Bt_ = BBASE(t); \
    const char* Au_ = ABASE((t) + 1); const char* Bu_ = BBASE((t) + 1); \
    /*P0*/ RD_Ax(A0, At_, 0); RD_Bx(B01, Bt_, 0); \
           BAR(); SETP1(); MMQ(A0, B01, 0, 0); SETP0(); BAR(); \
    /*P1*/ RD_Ax(A1, At_, 1); \
           BAR(); SETP1(); MMQ(A1, B01, 1, 0); SETP0(); BAR(); \
    /*P2*/ RD_Bx(B23, Bt_, 1); if (S1) { STG_A((t) + 2, 0); STG_A((t) + 2, 1); } \
           BAR(); SETP1(); MMQ(A1, B23, 1, 1); SETP0(); BAR(); \
    /*P3*/ if (S1) { STG_B((t) + 2, 0); STG_B((t) + 2, 1); } VMA; \
           BAR(); SETP1(); MMQ(A0, B23, 0, 1); SETP0(); BAR(); \
    /*P4*/ RD_Ax(A0, Au_, 0); RD_Bx(B01, Bu_, 0); \
           BAR(); SETP1(); MMQ(A0, B01, 0, 0); SETP0(); BAR(); \
    /*P5*/ RD_Ax(A1, Au_, 1); \
           BAR(); SETP1(); MMQ(A1, B01, 1, 0); SETP0(); BAR(); \
    /*P6*/ RD_Bx(B23, Bu_, 1); if (S2) { STG_A((t) + 3, 0); STG_A((t) + 3, 1); } \
           BAR(); SETP1(); MMQ(A1, B23, 1, 1); SETP0(); BAR(); \
    /*P7*/ if (S2) { STG_B((t) + 3, 0); STG_B((t) + 3, 1); } VMB; \
           BAR(); SETP1(); MMQ(A0, B23, 0, 1); SETP0(); BAR(); }

__global__ __launch_bounds__(512, 2) void gemm_kernel(const __bf16* __restrict__ A,
                                                      const __bf16* __restrict__ B,
                                                      __bf16* __restrict__ Y, long r0) {
  __shared__ __align__(16) __bf16 As[2 * 2 * 8192];   // [buf][half][128][64] swizzled
  __shared__ __align__(16) __bf16 Bs[2 * 2 * 8192];

  const int tid  = threadIdx.x;
  const int lane = tid & 63;
  const int wid  = tid >> 6;        // 0..7
  const int wr   = wid >> 2;        // 0..1  (M half)
  const int wc   = wid & 3;         // 0..3  (N quarter)

  // bijective XCD-aware swizzle (m204)
  const int nwg = gridDim.x;
  const int q8 = nwg >> 3, r8 = nwg & 7;
  const int xcd = blockIdx.x & 7, rest = blockIdx.x >> 3;
  const int wgid = (xcd < r8 ? xcd * (q8 + 1) : r8 * (q8 + 1) + (xcd - r8) * q8) + rest;
  const long m0 = (long)(wgid >> 4) * 256;   // chunk-local row tile
  const long n0 = (long)(wgid & 15) * 256;

  // staging: linear dest (row=tid/8, slot=tid&7); inverse-swizzled global source:
  // source col slot = (tid&7) ^ ((tid>>3)&7). (+64-row half: row mod 8 unchanged.)
  const int scol = (((tid & 7) ^ ((tid >> 3) & 7)) << 4);
  const char* Ag = (const char*)(A + (r0 + m0) * KDIM) + (long)(tid >> 3) * 2048 + scol;
  const char* Bg = (const char*)(B + n0 * KDIM) + (long)(tid >> 3) * 2048 + scol;
  char* Al = (char*)As + tid * 16;
  char* Bl = (char*)Bs + tid * 16;

  // fragment read addressing: byte = row*128 + (slot<<4), slot ^= (row&7) = (fr&7)
  const int fr  = lane & 15;
  const int sw  = (fr & 7) << 4;
  const int cb0 = (((lane >> 4) << 4)) ^ sw;
  const int cb1 = (64 | ((lane >> 4) << 4)) ^ sw;
  const int brow0 = (wc & 1) << 6;

  f32x4 acc[8][4];
  const f32x4 z = {0.f, 0.f, 0.f, 0.f};
#pragma unroll
  for (int i = 0; i < 8; ++i)
#pragma unroll
    for (int j = 0; j < 4; ++j) acc[i][j] = z;

  bf16x8 A0[4][2], A1[4][2], B01[2][2], B23[2][2];

  // ---- prologue: tiles 0 and 1 complete = 16 loads; vmcnt(8) -> tile0 landed.
  STG_A(0, 0); STG_A(0, 1); STG_B(0, 0); STG_B(0, 1);
  STG_A(1, 0); STG_A(1, 1); STG_B(1, 0); STG_B(1, 1);
  VMCNT(8);
  BAR();

#pragma unroll 1
  for (int tt = 0; tt < 7; ++tt) {
    const int t = tt * 2;
    TWOTILE(t, true, true, VMCNT(8), VMCNT(8));
  }
  TWOTILE(14, false, false, VMCNT(0), ((void)0));

  // ---- epilogue: C/D layout col=lane&15, row=(lane>>4)*4+reg
  const long mrow = m0 + wr * 128 + ((lane >> 4) << 2);
  const long ncol = n0 + wc * 64 + fr;
  __bf16* Yp = Y + mrow * NCOLS + ncol;
#pragma unroll
  for (int c = 0; c < 2; ++c)
#pragma unroll
    for (int mi = 0; mi < 4; ++mi)
#pragma unroll
      for (int nj = 0; nj < 4; ++nj)
#pragma unroll
        for (int r = 0; r < 4; ++r)
          Yp[(long)(c * 64 + mi * 16 + r) * NCOLS + nj * 16] = (__bf16)acc[c * 4 + mi][nj][r];
}

// ---------------- pass 2: row LN + gates + cell LN + output ----------------
__global__ __launch_bounds__(256) void pass2_kernel(const __bf16* __restrict__ Yw,
                                                    const float* __restrict__ bi,
                                                    const float* __restrict__ g_i2h,
                                                    const float* __restrict__ g_cell,
                                                    const float* __restrict__ b_cell,
                                                    float* __restrict__ out, long r0) {
  __shared__ float p0[4096];
  __shared__ float red[8];
  const int tid  = threadIdx.x;
  const long row = r0 + blockIdx.x;           // global row (t*64 + b)
  const bf16x8* yv = (const bf16x8*)(Yw + (long)blockIdx.x * NCOLS);

  // phase 1: p = y + bi (fp32), stash in LDS, accumulate stats over 4096
  float s = 0.f, ss = 0.f;
#pragma unroll
  for (int it = 0; it < 2; ++it) {
    const int ch = tid + it * 256;            // 8-elem chunk id, 0..511
    const bf16x8 v = yv[ch];
    const float4 b0 = ((const float4*)bi)[ch * 2];
    const float4 b1 = ((const float4*)bi)[ch * 2 + 1];
    float p[8];
    p[0] = (float)v[0] + b0.x;  p[1] = (float)v[1] + b0.y;
    p[2] = (float)v[2] + b0.z;  p[3] = (float)v[3] + b0.w;
    p[4] = (float)v[4] + b1.x;  p[5] = (float)v[5] + b1.y;
    p[6] = (float)v[6] + b1.z;  p[7] = (float)v[7] + b1.w;
#pragma unroll
    for (int u = 0; u < 8; ++u) {
      p0[ch * 8 + u] = p[u];
      s += p[u];
      ss += p[u] * p[u];
    }
  }
  block_reduce2(s, ss, red, tid);             // also fences p0 writes
  const float mu  = s * (1.f / 4096.f);
  const float var = (ss - 4096.f * mu * mu) * (1.f / 4095.f);   // ddof=1
  const float rs  = rsqrtf(var + 1e-6f);

  // phase 2: gates + cell accumulation (j = tid + u*256)
  float cc[4], oo[4];
  float s2 = 0.f, ss2 = 0.f;
#pragma unroll
  for (int u = 0; u < 4; ++u) {
    const int j = tid + u * 256;
    const float pf = g_i2h[1024 + j] * ((p0[1024 + j] - mu) * rs) + g_Cvec[1024 + j];
    const float po = g_i2h[2048 + j] * ((p0[2048 + j] - mu) * rs) + g_Cvec[2048 + j];
    const float pg = g_i2h[3072 + j] * ((p0[3072 + j] - mu) * rs) + g_Cvec[3072 + j];
    const float f  = 1.f / (1.f + __expf(-pf));
    oo[u] = 1.f / (1.f + __expf(-po));
    const float e2 = __expf(2.f * pg);
    const float gt = (e2 - 1.f) / (e2 + 1.f);   // tanh
    cc[u] = (1.f - f) * gt;                     // c0 = 0
    s2 += cc[u]; ss2 += cc[u] * cc[u];
  }
  block_reduce2(s2, ss2, red, tid);
  const float mu2  = s2 * (1.f / 1024.f);
  const float var2 = (ss2 - 1024.f * mu2 * mu2) * (1.f / 1023.f);  // ddof=1
  const float rs2  = rsqrtf(var2 + 1e-6f);

  const long obase = row * 1024;
#pragma unroll
  for (int u = 0; u < 4; ++u) {
    const int j = tid + u * 256;
    const float cn = g_cell[j] * ((cc[u] - mu2) * rs2) + b_cell[j];
    const float e2 = __expf(2.f * cn);
    const float th = (e2 - 1.f) / (e2 + 1.f);
    const float h  = oo[u] * th;
    out[obase + j] = h;
    if (row >= MROWS - 64)                       // t == T-1
      out[MROWS * 1024 + ((row - (MROWS - 64)) << 10) + j] = h;
  }
}

extern "C" void kernel_launch(void* const* d_in, const int* in_sizes, int n_in,
                              void* d_out, int out_size, void* d_ws, size_t ws_size,
                              hipStream_t stream) {
  (void)in_sizes; (void)n_in; (void)out_size;
  const float* x      = (const float*)d_in[0];
  const float* Wi     = (const float*)d_in[1];
  const float* bi     = (const float*)d_in[2];
  // d_in[3] = Wh : unused (h0 == 0)
  const float* bh     = (const float*)d_in[4];
  const float* g_i2h  = (const float*)d_in[5];
  const float* b_i2h  = (const float*)d_in[6];
  const float* g_h2h  = (const float*)d_in[7];
  const float* b_h2h  = (const float*)d_in[8];
  const float* g_cell = (const float*)d_in[9];
  const float* b_cell = (const float*)d_in[10];
  float* out = (float*)d_out;

  // All scratch in d_ws:
  //   [0, 64MB)     xb : x as bf16
  //   [64MB, 72MB)  wb : Wi as bf16
  //   [72MB, ...)   y  : Y chunk (<= 64MB)
  __bf16* xb = (__bf16*)d_ws;
  __bf16* wb = (__bf16*)((char*)d_ws + 67108864);
  __bf16* y  = (__bf16*)((char*)d_ws + 75497472);

  cast_kernel<<<2048, 256, 0, stream>>>((const float4*)x, (bf16x4*)xb, 33554432 / 4);
  cast_kernel<<<1024, 256, 0, stream>>>((const float4*)Wi, (bf16x4*)wb, 4194304 / 4);
  prep_kernel<<<1, 256, 0, stream>>>(bh, b_i2h, g_h2h, b_h2h);

  // chunk over M: cap at 8192 rows (Y chunk = 64 MB) so pass2 re-reads Y from
  // L2/L3 instead of HBM; also bounded by remaining workspace.
  long avail = (long)ws_size - 75497472L;
  long max_rows = (avail / (NCOLS * 2)) & ~255L;
  if (max_rows > 8192) max_rows = 8192;
  if (max_rows < 256)  max_rows = 256;   // assume ws >= ~74 MB
  for (long rbase = 0; rbase < MROWS; rbase += max_rows) {
    const long rows = (MROWS - rbase < max_rows) ? (MROWS - rbase) : max_rows;
    gemm_kernel<<<dim3((rows / 256) * 16), 512, 0, stream>>>(xb, wb, y, rbase);
    pass2_kernel<<<dim3(rows), 256, 0, stream>>>(y, bi, g_i2h, g_cell, b_cell, out, rbase);
  }
}

// Round 13
// 437.800 us; speedup vs baseline: 1.5747x; 1.0131x over previous
//
#include <hip/hip_runtime.h>
#include <hip/hip_bf16.h>
#include <stdint.h>

// LayerNormLSTM: T=512, B=64, I=1024, H=1024
// M = T*B = 32768 rows, N = 4*H = 4096, K = 1024.
// Reference degenerates (h0=c0=0, no scan):
//   h2h_vec = LN(bh; g_h2h, b_h2h)            (constant 4096-vec; Wh unused)
//   y       = x @ Wi^T                         (big GEMM)
//   p       = g_i2h * LNrow(y + bi) + (b_i2h + h2h_vec)
//   f,o     = sigmoid(p[H:2H]), sigmoid(p[2H:3H]); g = tanh(p[3H:])
//   c       = (1-f)*g ;  cn = LN_H(c) ;  h = o * tanh(cn)
// out = [h (T,B,H) ; h[-1] (B,H)]
//
// Scratch: d_ws only: [0,64MB) xb | [64MB,72MB) wb | [72MB,+64MB) Y
//
// R13: CLOBBERLESS WAITCNT. Root cause finally identified: every prior
// round's `asm volatile("s_waitcnt vmcnt(N)" ::: "memory")` makes the
// waitcnt-insertion pass treat the asm as a reader of ANY memory (incl. LDS
// dests of in-flight global_load_lds) -> it inserts its own vmcnt(0) DRAIN
// right before my counted wait. Every "counted" schedule since R5 was
// secretly drain0 — explaining 7 variants pinned at ~6300 cyc/tile and the
// R11 noread ablation's ~2000 cyc staging frame. The verified m201 template
// uses clobber-less waitcnt asm + raw builtin s_barrier (m218: counted vs
// drain0 = +38-73% on this HW). This round: R10 verbatim, minus the clobber.
// Ordering: gload_lds / barrier / volatile asm are chain-ordered at ISel
// (program order preserved); read->MFMA deps compiler-tracked; R9 rotation
// keeps overwrites >=1 phase-end barrier after last reader.

#define MROWS 32768L
#define NCOLS 4096
#define KDIM  1024

typedef __bf16 bf16x8 __attribute__((ext_vector_type(8)));
typedef __bf16 bf16x4 __attribute__((ext_vector_type(4)));
typedef float  f32x4  __attribute__((ext_vector_type(4)));

__device__ float g_Cvec[4096];   // b_i2h + h2h_vec (recomputed every launch)

__device__ __forceinline__ void gload16(char* lds, const char* g) {
  __builtin_amdgcn_global_load_lds(
      (const __attribute__((address_space(1))) char*)g,
      (__attribute__((address_space(3))) char*)lds, 16, 0, 0);
}

__device__ __forceinline__ void block_reduce2(float& a, float& b, float* red, int tid) {
#pragma unroll
  for (int m = 32; m > 0; m >>= 1) {
    a += __shfl_xor(a, m, 64);
    b += __shfl_xor(b, m, 64);
  }
  const int lane = tid & 63, wid = tid >> 6;
  if (lane == 0) { red[wid] = a; red[4 + wid] = b; }
  __syncthreads();
  a = red[0] + red[1] + red[2] + red[3];
  b = red[4] + red[5] + red[6] + red[7];
  __syncthreads();  // safe reuse of red[]
}

// ---------------- cast f32 -> bf16 (vectorized) ----------------
__global__ __launch_bounds__(256) void cast_kernel(const float4* __restrict__ in,
                                                   bf16x4* __restrict__ out, int n4) {
  int i = blockIdx.x * 256 + threadIdx.x;
  const int stride = gridDim.x * 256;
  for (; i < n4; i += stride) {
    const float4 v = in[i];
    bf16x4 o = { (__bf16)v.x, (__bf16)v.y, (__bf16)v.z, (__bf16)v.w };
    out[i] = o;
  }
}

// ---------------- prep: Cvec = b_i2h + LN(bh)*g_h2h + b_h2h ----------------
__global__ __launch_bounds__(256) void prep_kernel(const float* __restrict__ bh,
                                                   const float* __restrict__ b_i2h,
                                                   const float* __restrict__ g_h2h,
                                                   const float* __restrict__ b_h2h) {
  __shared__ float red[8];
  const int tid = threadIdx.x;
  float v[16];
  float s = 0.f, ss = 0.f;
#pragma unroll
  for (int u = 0; u < 16; ++u) {
    v[u] = bh[tid + u * 256];
    s += v[u]; ss += v[u] * v[u];
  }
  block_reduce2(s, ss, red, tid);
  const float mu  = s * (1.f / 4096.f);
  const float var = (ss - 4096.f * mu * mu) * (1.f / 4095.f);   // ddof=1
  const float rs  = rsqrtf(var + 1e-6f);
#pragma unroll
  for (int u = 0; u < 16; ++u) {
    const int g = tid + u * 256;
    g_Cvec[g] = b_i2h[g] + g_h2h[g] * ((v[u] - mu) * rs) + b_h2h[g];
  }
}

// ---------------- GEMM: Y[m][n] = sum_k A[m][k]*B[n][k]  (bf16 in, bf16 out) ----
// 256x256x64 tile, 8 waves (2Mx4N), 128KiB LDS [2 dbuf][2 half][128][64],
// full-rank LDS swizzle (slot ^= row&7; conflicts measured 0).
// MFMA 16x16x32; per wave 128x64: acc[8][4] f32x4.
//
// 8-phase schedule (2 K-tiles t,u=t+1 per iter), R9 race-free rotation:
//   P0: RD A0(8)+B01(4);              MFMA A0xB01
//   P1: RD A1(8);                     MFMA A1xB01
//   P2: RD B23(4); STG A(t+2) h0+h1;  MFMA A1xB23
//   P3: STG B(t+2) h0+h1; vmcnt(8);   MFMA A0xB23
//   P4..P7: same for tile u, staging t+3.
// Ledger: A buf[t] last read P1 -> staged P2.  B buf[t] last read P2 ->
//   staged P3.  vmcnt(8)@P3 keeps only {A,B}(t+2) -> tile t+1 landed before
//   P4; vmcnt(8)@P7 -> t+2 landed before next P0. Prologue 16 loads +
//   vmcnt(8) -> tile0 landed. Tail t=14: no stages; P3 vmcnt(0).

#define BAR()   __builtin_amdgcn_s_barrier()
#define VMCNT(n) asm volatile("s_waitcnt vmcnt(" #n ")")   // NO memory clobber!
#define SETP1() __builtin_amdgcn_s_setprio(1)
#define SETP0() __builtin_amdgcn_s_setprio(0)

#define STG_A(s, h) { char* d_ = Al + (((s) & 1) << 15) + ((h) << 14); \
    const char* g_ = Ag + (long)(h) * 262144 + (s) * 128; \
    gload16(d_, g_); gload16(d_ + 8192, g_ + 131072); }

#define STG_B(s, h) { char* d_ = Bl + (((s) & 1) << 15) + ((h) << 14); \
    const char* g_ = Bg + (long)(h) * 262144 + (s) * 128; \
    gload16(d_, g_); gload16(d_ + 8192, g_ + 131072); }

#define ABASE(t) ((const char*)As + (((t) & 1) << 15) + (wr << 14))
#define BBASE(t) ((const char*)Bs + (((t) & 1) << 15) + ((wc >> 1) << 14))

#define RD_Ax(arr, Ahalf, c) { _Pragma("unroll") for (int mi_ = 0; mi_ < 4; ++mi_) { \
    const char* p_ = (Ahalf) + (((c) * 64 + mi_ * 16 + fr) << 7); \
    arr[mi_][0] = *(const bf16x8*)(p_ + cb0); \
    arr[mi_][1] = *(const bf16x8*)(p_ + cb1); } }

#define RD_Bx(arr, Bhalf, g) { _Pragma("unroll") for (int nj_ = 0; nj_ < 2; ++nj_) { \
    const char* p_ = (Bhalf) + ((brow0 + (g) * 32 + nj_ * 16 + fr) << 7); \
    arr[nj_][0] = *(const bf16x8*)(p_ + cb0); \
    arr[nj_][1] = *(const bf16x8*)(p_ + cb1); } }

#define MMQ(X, Y, c, g) { _Pragma("unroll") for (int mi_ = 0; mi_ < 4; ++mi_) { \
    _Pragma("unroll") for (int nj_ = 0; nj_ < 2; ++nj_) { \
      acc[(c)*4+mi_][(g)*2+nj_] = __builtin_amdgcn_mfma_f32_16x16x32_bf16( \
          X[mi_][0], Y[nj_][0], acc[(c)*4+mi_][(g)*2+nj_], 0, 0, 0); \
      acc[(c)*4+mi_][(g)*2+nj_] = __builtin_amdgcn_mfma_f32_16x16x32_bf16( \
          X[mi_][1], Y[nj_][1], acc[(c)*4+mi_][(g)*2+nj_], 0, 0, 0); } } }

// S1 = (t+2 < 16), S2 = (t+3 < 16); VMA at P3, VMB at P7.
#define TWOTILE(t, S1, S2, VMA, VMB) { \
    const char* At_ = ABASE(t); const char* Bt_ = BBASE(t); \
    const char* Au_ = ABASE((t) + 1); const char* Bu_ = BBASE((t) + 1); \
    /*P0*/ RD_Ax(A0, At_, 0); RD_Bx(B01, Bt_, 0); \
           BAR(); SETP1(); MMQ(A0, B01, 0, 0); SETP0(); BAR(); \
    /*P1*/ RD_Ax(A1, At_, 1); \
           BAR(); SETP1(); MMQ(A1, B01, 1, 0); SETP0(); BAR(); \
    /*P2*/ RD_Bx(B23, Bt_, 1); if (S1) { STG_A((t) + 2, 0); STG_A((t) + 2, 1); } \
           BAR(); SETP1(); MMQ(A1, B23, 1, 1); SETP0(); BAR(); \
    /*P3*/ if (S1) { STG_B((t) + 2, 0); STG_B((t) + 2, 1); } VMA; \
           BAR(); SETP1(); MMQ(A0, B23, 0, 1); SETP0(); BAR(); \
    /*P4*/ RD_Ax(A0, Au_, 0); RD_Bx(B01, Bu_, 0); \
           BAR(); SETP1(); MMQ(A0, B01, 0, 0); SETP0(); BAR(); \
    /*P5*/ RD_Ax(A1, Au_, 1); \
           BAR(); SETP1(); MMQ(A1, B01, 1, 0); SETP0(); BAR(); \
    /*P6*/ RD_Bx(B23, Bu_, 1); if (S2) { STG_A((t) + 3, 0); STG_A((t) + 3, 1); } \
           BAR(); SETP1(); MMQ(A1, B23, 1, 1); SETP0(); BAR(); \
    /*P7*/ if (S2) { STG_B((t) + 3, 0); STG_B((t) + 3, 1); } VMB; \
           BAR(); SETP1(); MMQ(A0, B23, 0, 1); SETP0(); BAR(); }

__global__ __launch_bounds__(512, 2) void gemm_kernel(const __bf16* __restrict__ A,
                                                      const __bf16* __restrict__ B,
                                                      __bf16* __restrict__ Y, long r0) {
  __shared__ __align__(16) __bf16 As[2 * 2 * 8192];   // [buf][half][128][64] swizzled
  __shared__ __align__(16) __bf16 Bs[2 * 2 * 8192];

  const int tid  = threadIdx.x;
  const int lane = tid & 63;
  const int wid  = tid >> 6;        // 0..7
  const int wr   = wid >> 2;        // 0..1  (M half)
  const int wc   = wid & 3;         // 0..3  (N quarter)

  // bijective XCD-aware swizzle (m204)
  const int nwg = gridDim.x;
  const int q8 = nwg >> 3, r8 = nwg & 7;
  const int xcd = blockIdx.x & 7, rest = blockIdx.x >> 3;
  const int wgid = (xcd < r8 ? xcd * (q8 + 1) : r8 * (q8 + 1) + (xcd - r8) * q8) + rest;
  const long m0 = (long)(wgid >> 4) * 256;   // chunk-local row tile
  const long n0 = (long)(wgid & 15) * 256;

  // staging: linear dest (row=tid/8, slot=tid&7); inverse-swizzled global source:
  // source col slot = (tid&7) ^ ((tid>>3)&7). (+64-row half: row mod 8 unchanged.)
  const int scol = (((tid & 7) ^ ((tid >> 3) & 7)) << 4);
  const char* Ag = (const char*)(A + (r0 + m0) * KDIM) + (long)(tid >> 3) * 2048 + scol;
  const char* Bg = (const char*)(B + n0 * KDIM) + (long)(tid >> 3) * 2048 + scol;
  char* Al = (char*)As + tid * 16;
  char* Bl = (char*)Bs + tid * 16;

  // fragment read addressing: byte = row*128 + (slot<<4), slot ^= (row&7) = (fr&7)
  const int fr  = lane & 15;
  const int sw  = (fr & 7) << 4;
  const int cb0 = (((lane >> 4) << 4)) ^ sw;
  const int cb1 = (64 | ((lane >> 4) << 4)) ^ sw;
  const int brow0 = (wc & 1) << 6;

  f32x4 acc[8][4];
  const f32x4 z = {0.f, 0.f, 0.f, 0.f};
#pragma unroll
  for (int i = 0; i < 8; ++i)
#pragma unroll
    for (int j = 0; j < 4; ++j) acc[i][j] = z;

  bf16x8 A0[4][2], A1[4][2], B01[2][2], B23[2][2];

  // ---- prologue: tiles 0 and 1 complete = 16 loads; vmcnt(8) -> tile0 landed.
  STG_A(0, 0); STG_A(0, 1); STG_B(0, 0); STG_B(0, 1);
  STG_A(1, 0); STG_A(1, 1); STG_B(1, 0); STG_B(1, 1);
  VMCNT(8);
  BAR();

#pragma unroll 1
  for (int tt = 0; tt < 7; ++tt) {
    const int t = tt * 2;
    TWOTILE(t, true, true, VMCNT(8), VMCNT(8));
  }
  TWOTILE(14, false, false, VMCNT(0), ((void)0));

  // ---- epilogue: C/D layout col=lane&15, row=(lane>>4)*4+reg
  const long mrow = m0 + wr * 128 + ((lane >> 4) << 2);
  const long ncol = n0 + wc * 64 + fr;
  __bf16* Yp = Y + mrow * NCOLS + ncol;
#pragma unroll
  for (int c = 0; c < 2; ++c)
#pragma unroll
    for (int mi = 0; mi < 4; ++mi)
#pragma unroll
      for (int nj = 0; nj < 4; ++nj)
#pragma unroll
        for (int r = 0; r < 4; ++r)
          Yp[(long)(c * 64 + mi * 16 + r) * NCOLS + nj * 16] = (__bf16)acc[c * 4 + mi][nj][r];
}

// ---------------- pass 2: row LN + gates + cell LN + output ----------------
__global__ __launch_bounds__(256) void pass2_kernel(const __bf16* __restrict__ Yw,
                                                    const float* __restrict__ bi,
                                                    const float* __restrict__ g_i2h,
                                                    const float* __restrict__ g_cell,
                                                    const float* __restrict__ b_cell,
                                                    float* __restrict__ out, long r0) {
  __shared__ float p0[4096];
  __shared__ float red[8];
  const int tid  = threadIdx.x;
  const long row = r0 + blockIdx.x;           // global row (t*64 + b)
  const bf16x8* yv = (const bf16x8*)(Yw + (long)blockIdx.x * NCOLS);

  // phase 1: p = y + bi (fp32), stash in LDS, accumulate stats over 4096
  float s = 0.f, ss = 0.f;
#pragma unroll
  for (int it = 0; it < 2; ++it) {
    const int ch = tid + it * 256;            // 8-elem chunk id, 0..511
    const bf16x8 v = yv[ch];
    const float4 b0 = ((const float4*)bi)[ch * 2];
    const float4 b1 = ((const float4*)bi)[ch * 2 + 1];
    float p[8];
    p[0] = (float)v[0] + b0.x;  p[1] = (float)v[1] + b0.y;
    p[2] = (float)v[2] + b0.z;  p[3] = (float)v[3] + b0.w;
    p[4] = (float)v[4] + b1.x;  p[5] = (float)v[5] + b1.y;
    p[6] = (float)v[6] + b1.z;  p[7] = (float)v[7] + b1.w;
#pragma unroll
    for (int u = 0; u < 8; ++u) {
      p0[ch * 8 + u] = p[u];
      s += p[u];
      ss += p[u] * p[u];
    }
  }
  block_reduce2(s, ss, red, tid);             // also fences p0 writes
  const float mu  = s * (1.f / 4096.f);
  const float var = (ss - 4096.f * mu * mu) * (1.f / 4095.f);   // ddof=1
  const float rs  = rsqrtf(var + 1e-6f);

  // phase 2: gates + cell accumulation (j = tid + u*256)
  float cc[4], oo[4];
  float s2 = 0.f, ss2 = 0.f;
#pragma unroll
  for (int u = 0; u < 4; ++u) {
    const int j = tid + u * 256;
    const float pf = g_i2h[1024 + j] * ((p0[1024 + j] - mu) * rs) + g_Cvec[1024 + j];
    const float po = g_i2h[2048 + j] * ((p0[2048 + j] - mu) * rs) + g_Cvec[2048 + j];
    const float pg = g_i2h[3072 + j] * ((p0[3072 + j] - mu) * rs) + g_Cvec[3072 + j];
    const float f  = 1.f / (1.f + __expf(-pf));
    oo[u] = 1.f / (1.f + __expf(-po));
    const float e2 = __expf(2.f * pg);
    const float gt = (e2 - 1.f) / (e2 + 1.f);   // tanh
    cc[u] = (1.f - f) * gt;                     // c0 = 0
    s2 += cc[u]; ss2 += cc[u] * cc[u];
  }
  block_reduce2(s2, ss2, red, tid);
  const float mu2  = s2 * (1.f / 1024.f);
  const float var2 = (ss2 - 1024.f * mu2 * mu2) * (1.f / 1023.f);  // ddof=1
  const float rs2  = rsqrtf(var2 + 1e-6f);

  const long obase = row * 1024;
#pragma unroll
  for (int u = 0; u < 4; ++u) {
    const int j = tid + u * 256;
    const float cn = g_cell[j] * ((cc[u] - mu2) * rs2) + b_cell[j];
    const float e2 = __expf(2.f * cn);
    const float th = (e2 - 1.f) / (e2 + 1.f);
    const float h  = oo[u] * th;
    out[obase + j] = h;
    if (row >= MROWS - 64)                       // t == T-1
      out[MROWS * 1024 + ((row - (MROWS - 64)) << 10) + j] = h;
  }
}

extern "C" void kernel_launch(void* const* d_in, const int* in_sizes, int n_in,
                              void* d_out, int out_size, void* d_ws, size_t ws_size,
                              hipStream_t stream) {
  (void)in_sizes; (void)n_in; (void)out_size;
  const float* x      = (const float*)d_in[0];
  const float* Wi     = (const float*)d_in[1];
  const float* bi     = (const float*)d_in[2];
  // d_in[3] = Wh : unused (h0 == 0)
  const float* bh     = (const float*)d_in[4];
  const float* g_i2h  = (const float*)d_in[5];
  const float* b_i2h  = (const float*)d_in[6];
  const float* g_h2h  = (const float*)d_in[7];
  const float* b_h2h  = (const float*)d_in[8];
  const float* g_cell = (const float*)d_in[9];
  const float* b_cell = (const float*)d_in[10];
  float* out = (float*)d_out;

  // All scratch in d_ws:
  //   [0, 64MB)     xb : x as bf16
  //   [64MB, 72MB)  wb : Wi as bf16
  //   [72MB, ...)   y  : Y chunk (<= 64MB)
  __bf16* xb = (__bf16*)d_ws;
  __bf16* wb = (__bf16*)((char*)d_ws + 67108864);
  __bf16* y  = (__bf16*)((char*)d_ws + 75497472);

  cast_kernel<<<2048, 256, 0, stream>>>((const float4*)x, (bf16x4*)xb, 33554432 / 4);
  cast_kernel<<<1024, 256, 0, stream>>>((const float4*)Wi, (bf16x4*)wb, 4194304 / 4);
  prep_kernel<<<1, 256, 0, stream>>>(bh, b_i2h, g_h2h, b_h2h);

  // chunk over M: cap at 8192 rows (Y chunk = 64 MB) so pass2 re-reads Y from
  // L2/L3 instead of HBM; also bounded by remaining workspace.
  long avail = (long)ws_size - 75497472L;
  long max_rows = (avail / (NCOLS * 2)) & ~255L;
  if (max_rows > 8192) max_rows = 8192;
  if (max_rows < 256)  max_rows = 256;   // assume ws >= ~74 MB
  for (long rbase = 0; rbase < MROWS; rbase += max_rows) {
    const long rows = (MROWS - rbase < max_rows) ? (MROWS - rbase) : max_rows;
    gemm_kernel<<<dim3((rows / 256) * 16), 512, 0, stream>>>(xb, wb, y, rbase);
    pass2_kernel<<<dim3(rows), 256, 0, stream>>>(y, bi, g_i2h, g_cell, b_cell, out, rbase);
  }
}